// Round 7
// baseline (527.358 us; speedup 1.0000x reference)
//
#include <hip/hip_runtime.h>
#include <hip/hip_bf16.h>
#include <math.h>

#define B_ 64
#define S_ 2048
#define D_ 512
#define A_ 512

typedef __attribute__((ext_vector_type(8))) short short8;
typedef __attribute__((ext_vector_type(4))) short short4b;
typedef __attribute__((ext_vector_type(4))) float f32x4;

#define SB() __builtin_amdgcn_sched_barrier(0)

__device__ __forceinline__ short bf16b(float f) {
    __hip_bfloat16 h = __float2bfloat16(f);
    union { __hip_bfloat16 h; short s; } u; u.h = h;
    return u.s;
}

__device__ __forceinline__ float tanh_fast(float x) {
    float e = __expf(2.0f * x);
    return 1.0f - 2.0f / (e + 1.0f);
}

// async global->LDS, 16B per lane; LDS dest = wave-uniform base + lane*16
__device__ __forceinline__ void llds16(const void* g, void* l) {
    __builtin_amdgcn_global_load_lds(
        (const __attribute__((address_space(1))) unsigned int*)g,
        (__attribute__((address_space(3))) unsigned int*)l, 16, 0, 0);
}

// ---------------------------------------------------------------------------
// Kernel 1 (merged): blocks 0..63   -> htWb = input@Wh + b_attn
//                    blocks 64..127 -> staged B image:
//   staged[kt][g][lane][0:8] (shorts) = bf16 Ws[k][a] with
//     a = g*16 + (lane>>2), c = lane&3, csw = c ^ ((a>>1)&3),
//     k = kt*32 + csw*8 + 0..7
//   i.e. exactly the byte order global_load_lds writes into Bb, so the
//   k_score staging loads are fully contiguous 1KB per wave-instruction.
// ---------------------------------------------------------------------------
__global__ __launch_bounds__(256) void k_prep(const float* __restrict__ input,
                                              const float* __restrict__ Wh,
                                              const float* __restrict__ b_attn,
                                              const float* __restrict__ Ws,
                                              float* __restrict__ htWb,
                                              short* __restrict__ staged) {
    const int t = threadIdx.x;
    if (blockIdx.x < 64) {
        __shared__ float xin[512];
        const int b = blockIdx.x;
        xin[t] = input[b * D_ + t];
        xin[t + 256] = input[b * D_ + t + 256];
        __syncthreads();
        float a0 = 0.f, a1 = 0.f;
#pragma unroll 8
        for (int d = 0; d < D_; ++d) {
            const float xv = xin[d];
            a0 += xv * Wh[d * A_ + t];
            a1 += xv * Wh[d * A_ + t + 256];
        }
        htWb[b * A_ + t] = a0 + b_attn[t];
        htWb[b * A_ + t + 256] = a1 + b_attn[t + 256];
    } else {
        const int blk = blockIdx.x - 64;
        const int bx = blk & 7, by = blk >> 3;
        const int r0 = by * 64, c0 = bx * 64;  // r = k (D dim), c = a (A dim)
        __shared__ short tile[64][72];         // [a_rel][k_rel]
        const int row = t >> 4, col4 = (t & 15) * 4;
#pragma unroll
        for (int i = 0; i < 4; ++i) {
            const float4 v = *(const float4*)&Ws[(r0 + row + i * 16) * A_ + c0 + col4];
            tile[col4 + 0][row + i * 16] = bf16b(v.x);
            tile[col4 + 1][row + i * 16] = bf16b(v.y);
            tile[col4 + 2][row + i * 16] = bf16b(v.z);
            tile[col4 + 3][row + i * 16] = bf16b(v.w);
        }
        __syncthreads();
        // write 4-k chunks (8B) to staged positions
        const int k0 = r0 + col4;                     // 4 consecutive k, 8-granule aligned to 0/4
        const int kt = k0 >> 5;
        const int csw = (k0 >> 3) & 3;
#pragma unroll
        for (int i = 0; i < 4; ++i) {
            const int arel = row + i * 16;
            const int a = c0 + arel;
            short4b o;
            o.x = tile[arel][col4 + 0];
            o.y = tile[arel][col4 + 1];
            o.z = tile[arel][col4 + 2];
            o.w = tile[arel][col4 + 3];
            const int slot = (a & 15) * 4 + (csw ^ ((a >> 1) & 3));
            *(short4b*)&staged[kt * 16384 + (a >> 4) * 512 + slot * 8 + (k0 & 7)] = o;
        }
    }
}

// ---------------------------------------------------------------------------
// Kernel 2: scores[b][s] = sum_a va[a]*tanh(htWb[b][a] + sum_d ctx[b][s][d]*Ws[d][a])
//   128 rows x 512 cols, BK=32. 4-deep B pipeline (Bb[4]), raw barriers only
//   (NO __syncthreads in the loop -> no hidden vmcnt(0) drain), single
//   counted wait vmcnt(4) per kt. B staging reads contiguous 1KB/instr from
//   the pre-swizzled staged image; A loads are 8 lanes/row (128B segments).
// ---------------------------------------------------------------------------
__global__ __launch_bounds__(512, 2)
void k_score4(const float* __restrict__ ctx, const short* __restrict__ staged,
              const float* __restrict__ htWb, const float* __restrict__ va,
              float* __restrict__ scores) {
    __shared__ __align__(16) short Bb[4][512 * 32];   // 4 x 32KB
    __shared__ __align__(16) short Ab[128 * 32];      // 8KB single
    __shared__ float hv_s[512];
    __shared__ float va_s[512];
    __shared__ float scores_s[128];
    __shared__ float rowsum_s[128];

    const int tid = threadIdx.x;
    const int w = tid >> 6, lane = tid & 63;
    const int wm = w >> 2, wn = w & 3;            // 2 row-halves x 4 col-groups
    const int blk = blockIdx.x;
    const int b = blk >> 4;                       // 16 tiles of 128 rows per batch
    const int s0 = (blk & 15) * 128;
    const long rowbase = (long)b * S_ + s0;

    hv_s[tid] = htWb[b * A_ + tid];
    va_s[tid] = va[tid];
    if (tid < 128) scores_s[tid] = 0.f;

    // A mapping: 8 lanes per row; thread handles rows (tid>>3) and (tid>>3)+64
    const int row0 = tid >> 3, q = tid & 7;
    const int row1 = row0 + 64;
    const float* aSrc0 = ctx + (rowbase + row0) * (long)D_ + q * 4;
    const float* aSrc1 = aSrc0 + 64 * D_;
    float rs0 = 0.f, rs1 = 0.f;

    f32x4 acc[4][8];
#pragma unroll
    for (int i = 0; i < 4; ++i)
#pragma unroll
        for (int j = 0; j < 8; ++j)
#pragma unroll
            for (int e = 0; e < 4; ++e) acc[i][j][e] = 0.f;

    // contiguous B stage: 4 llds16 per wave, 1KB each
#define STAGE_B4(buf, kt_)                                                    \
    {                                                                         \
        _Pragma("unroll") for (int j = 0; j < 4; ++j) {                       \
            const int g = w * 4 + j;                                          \
            llds16(staged + (kt_) * 16384 + g * 512 + lane * 8,               \
                   (void*)&Bb[buf][g * 512]);                                 \
        }                                                                     \
    }

    // A write: fp32->bf16 + swizzled 8B writes for rows row0 and row1
#define STAGE_A_WRITE(v0, v1)                                                 \
    {                                                                         \
        rs0 += (v0)[0] + (v0)[1] + (v0)[2] + (v0)[3];                         \
        rs1 += (v1)[0] + (v1)[1] + (v1)[2] + (v1)[3];                         \
        short4b o0, o1;                                                       \
        o0.x = bf16b((v0)[0]); o0.y = bf16b((v0)[1]);                         \
        o0.z = bf16b((v0)[2]); o0.w = bf16b((v0)[3]);                         \
        o1.x = bf16b((v1)[0]); o1.y = bf16b((v1)[1]);                         \
        o1.z = bf16b((v1)[2]); o1.w = bf16b((v1)[3]);                         \
        const int cq = q >> 1, sub = q & 1;                                   \
        *(short4b*)((char*)Ab + row0 * 64 + ((cq ^ ((row0 >> 1) & 3)) * 16) + sub * 8) = o0; \
        *(short4b*)((char*)Ab + row1 * 64 + ((cq ^ ((row1 >> 1) & 3)) * 16) + sub * 8) = o1; \
    }

    // ---- prologue: A(0) staged via plain loads; B(0..2) issued; retire B0
    {
        const f32x4 v0 = *(const f32x4*)(aSrc0);
        const f32x4 v1 = *(const f32x4*)(aSrc1);
        STAGE_A_WRITE(v0, v1);
    }
    STAGE_B4(0, 0);
    STAGE_B4(1, 1);
    STAGE_B4(2, 2);
    asm volatile("s_waitcnt vmcnt(8)" ::: "memory");   // retire B0; B1,B2 in flight
    SB();
    asm volatile("s_waitcnt lgkmcnt(0)" ::: "memory");
    SB();
    __builtin_amdgcn_s_barrier();
    SB();

    for (int kt = 0; kt < 16; ++kt) {
        const int cur = kt & 3;
        f32x4 nv0, nv1;
        if (kt < 15) {
            // A(kt+1) FIRST (so vmcnt(4) later retires it without draining B(kt+3))
            const float* p0 = aSrc0 + (kt + 1) * 32;
            const float* p1 = aSrc1 + (kt + 1) * 32;
            asm volatile("global_load_dwordx4 %0, %1, off" : "=v"(nv0) : "v"(p0));
            asm volatile("global_load_dwordx4 %0, %1, off" : "=v"(nv1) : "v"(p1));
            SB();
        }
        if (kt < 13) {
            STAGE_B4((kt + 3) & 3, kt + 3);
            SB();
        }
        // MFMA burst from Ab + Bb[cur]
        __builtin_amdgcn_s_setprio(1);
        {
            short8 af[4];
#pragma unroll
            for (int mf = 0; mf < 4; ++mf) {
                const int r = wm * 64 + mf * 16 + (lane & 15);
                const int c = lane >> 4;
                const int csw = c ^ ((r >> 1) & 3);
                af[mf] = *(const short8*)((const char*)Ab + r * 64 + csw * 16);
            }
#pragma unroll
            for (int nf = 0; nf < 8; ++nf) {
                const int a = wn * 128 + nf * 16 + (lane & 15);
                const int c = lane >> 4;
                const int csw = c ^ ((a >> 1) & 3);
                const short8 bf =
                    *(const short8*)((const char*)&Bb[cur][0] + a * 64 + csw * 16);
#pragma unroll
                for (int mf = 0; mf < 4; ++mf)
                    acc[mf][nf] = __builtin_amdgcn_mfma_f32_16x16x32_bf16(
                        af[mf], bf, acc[mf][nf], 0, 0, 0);
            }
        }
        __builtin_amdgcn_s_setprio(0);
        // barrier1: Ab/Bb reads done block-wide; NO vmem drain
        asm volatile("s_waitcnt lgkmcnt(0)" ::: "memory");
        SB();
        __builtin_amdgcn_s_barrier();
        SB();
        if (kt < 15) {
            // retire A(kt+1) (+2 oldest B tiles); newest B tile stays in flight
            if (kt < 13) {
                asm volatile("s_waitcnt vmcnt(4)" ::: "memory");
            } else {
                asm volatile("s_waitcnt vmcnt(0)" ::: "memory");
            }
            SB();
            STAGE_A_WRITE(nv0, nv1);
            // barrier2: Ab writes visible; still NO vmem drain
            asm volatile("s_waitcnt lgkmcnt(0)" ::: "memory");
            SB();
            __builtin_amdgcn_s_barrier();
            SB();
        }
    }

    // padding-mask row sums (8 lanes per row)
    rs0 += __shfl_xor(rs0, 1); rs0 += __shfl_xor(rs0, 2); rs0 += __shfl_xor(rs0, 4);
    rs1 += __shfl_xor(rs1, 1); rs1 += __shfl_xor(rs1, 2); rs1 += __shfl_xor(rs1, 4);
    if ((tid & 7) == 0) {
        rowsum_s[row0] = rs0;
        rowsum_s[row1] = rs1;
    }

    // epilogue: score_row = sum_a va[a]*tanh(htWb[a] + acc)
    float hv[8], vv[8];
#pragma unroll
    for (int nf = 0; nf < 8; ++nf) {
        const int col = wn * 128 + nf * 16 + (lane & 15);
        hv[nf] = hv_s[col];
        vv[nf] = va_s[col];
    }
#pragma unroll
    for (int mf = 0; mf < 4; ++mf) {
#pragma unroll
        for (int e = 0; e < 4; ++e) {
            float p = 0.f;
#pragma unroll
            for (int nf = 0; nf < 8; ++nf)
                p += vv[nf] * tanh_fast(hv[nf] + acc[mf][nf][e]);
            p += __shfl_xor(p, 1);
            p += __shfl_xor(p, 2);
            p += __shfl_xor(p, 4);
            p += __shfl_xor(p, 8);
            if ((lane & 15) == 0) {
                const int row = wm * 64 + mf * 16 + (lane >> 4) * 4 + e;
                atomicAdd(&scores_s[row], p);
            }
        }
    }
    __syncthreads();

    if (tid < 128) {
        float sc = scores_s[tid];
        if (rowsum_s[tid] == 0.0f) sc = -__builtin_inff();
        scores[rowbase + tid] = sc;
    }
}

// ---------------------------------------------------------------------------
// Kernel 3: in-place softmax over S per batch row (scores -> attn_dist)
// ---------------------------------------------------------------------------
__global__ __launch_bounds__(256) void k_softmax(float* __restrict__ dist) {
    const int b = blockIdx.x, t = threadIdx.x;
    float* p = dist + b * S_;
    float v[8];
    float m = -__builtin_inff();
#pragma unroll
    for (int i = 0; i < 8; ++i) {
        v[i] = p[t + i * 256];
        m = fmaxf(m, v[i]);
    }
#pragma unroll
    for (int mask = 1; mask < 64; mask <<= 1) m = fmaxf(m, __shfl_xor(m, mask));
    __shared__ float redm[4], reds[4];
    if ((t & 63) == 0) redm[t >> 6] = m;
    __syncthreads();
    m = fmaxf(fmaxf(redm[0], redm[1]), fmaxf(redm[2], redm[3]));
    float sum = 0.f;
#pragma unroll
    for (int i = 0; i < 8; ++i) {
        v[i] = __expf(v[i] - m);
        sum += v[i];
    }
#pragma unroll
    for (int mask = 1; mask < 64; mask <<= 1) sum += __shfl_xor(sum, mask);
    if ((t & 63) == 0) reds[t >> 6] = sum;
    __syncthreads();
    sum = reds[0] + reds[1] + reds[2] + reds[3];
    const float inv = 1.0f / sum;
#pragma unroll
    for (int i = 0; i < 8; ++i) p[t + i * 256] = v[i] * inv;
}

// ---------------------------------------------------------------------------
// Kernel 4: partial[b][ch][d] = sum_{s in 128-chunk} p[b][s] * ctx[b][s][d]
// ---------------------------------------------------------------------------
__global__ __launch_bounds__(256) void k_wsum(const float* __restrict__ ctx,
                                              const float* __restrict__ dist,
                                              float* __restrict__ partial) {
    const int ch = blockIdx.x, b = blockIdx.y;
    const int t = threadIdx.x;
    const int half = t >> 7;           // rows 0-63 / 64-127
    const int td = (t & 127) * 4;
    __shared__ float ps[128];
    __shared__ f32x4 red[128];
    if (t < 128) ps[t] = dist[b * S_ + ch * 128 + t];
    __syncthreads();
    const float* cbase = ctx + ((long)b * S_ + ch * 128 + half * 64) * D_ + td;
    f32x4 a = {0.f, 0.f, 0.f, 0.f};
#pragma unroll 8
    for (int r = 0; r < 64; ++r) {
        const f32x4 cv = *(const f32x4*)(cbase + (long)r * D_);
        const float pw = ps[half * 64 + r];
        a[0] += pw * cv[0];
        a[1] += pw * cv[1];
        a[2] += pw * cv[2];
        a[3] += pw * cv[3];
    }
    if (half == 1) red[t & 127] = a;
    __syncthreads();
    if (half == 0) {
        const f32x4 o = red[t];
        a[0] += o[0]; a[1] += o[1]; a[2] += o[2]; a[3] += o[3];
        *(f32x4*)&partial[((b * 16 + ch) * D_) + td] = a;
    }
}

// ---------------------------------------------------------------------------
// Kernel 5: attn_context[b][d] = sum_ch partial[b][ch][d]
// ---------------------------------------------------------------------------
__global__ __launch_bounds__(128) void k_reduce(const float* __restrict__ partial,
                                                float* __restrict__ out) {
    const int b = blockIdx.x, t = threadIdx.x;
    float ax = 0.f, ay = 0.f, az = 0.f, aw = 0.f;
#pragma unroll
    for (int j = 0; j < 16; ++j) {
        const float4 v = *(const float4*)&partial[((b * 16 + j) * D_) + t * 4];
        ax += v.x; ay += v.y; az += v.z; aw += v.w;
    }
    float4 o; o.x = ax; o.y = ay; o.z = az; o.w = aw;
    *(float4*)&out[b * D_ + t * 4] = o;
}

// ---------------------------------------------------------------------------
extern "C" void kernel_launch(void* const* d_in, const int* in_sizes, int n_in,
                              void* d_out, int out_size, void* d_ws, size_t ws_size,
                              hipStream_t stream) {
    (void)in_sizes; (void)n_in; (void)out_size; (void)ws_size;
    const float* input  = (const float*)d_in[0];
    const float* ctx    = (const float*)d_in[1];
    const float* Wh     = (const float*)d_in[2];
    const float* Ws     = (const float*)d_in[3];
    const float* b_attn = (const float*)d_in[4];
    const float* va     = (const float*)d_in[5];

    float* out = (float*)d_out;
    float* attn_ctx  = out;              // [64, 512]
    float* attn_dist = out + B_ * D_;    // [64, 2048] (raw scores first, softmax in place)

    char* ws = (char*)d_ws;
    float* htWb    = (float*)ws;                          // 64*512*4   = 128 KB
    short* staged  = (short*)(ws + 131072);               // 512*512*2  = 512 KB (B image)
    float* partial = (float*)(ws + 131072 + 524288);      // 64*16*512*4 = 2 MB

    k_prep<<<128, 256, 0, stream>>>(input, Wh, b_attn, Ws, htWb, staged);
    k_score4<<<1024, 512, 0, stream>>>(ctx, staged, htWb, va, attn_dist);
    k_softmax<<<64, 256, 0, stream>>>(attn_dist);
    k_wsum<<<dim3(16, 64), 256, 0, stream>>>(ctx, attn_dist, partial);
    k_reduce<<<64, 128, 0, stream>>>(partial, attn_ctx);
}